// Round 2
// baseline (360.414 us; speedup 1.0000x reference)
//
#include <hip/hip_runtime.h>
#include <cstdint>

#define HW 200704      // 448*448
#define IMG_W 448
#define NCLS 20
#define NDIM 256
#define CAPG 2560      // candidate cap per (b,c); mean 2007, sd 45 at T=0.99
#define TFILT 0.99f
#define LK 257         // padded LDS stride (257 mod 32 == 1 -> conflict-free)

// ---------------------------------------------------------------------------
// K0: transpose fmap [B,256,784] -> fmapT [B,784,256]
__global__ __launch_bounds__(256) void k_transpose(const float* __restrict__ fmap,
                                                   float* __restrict__ fmapT) {
  int g = blockIdx.x * 256 + threadIdx.x;   // 401408 total
  int d = g & 255;
  int s = (g >> 8) % 784;
  int b = g / 200704;
  fmapT[g] = fmap[(b * 256 + d) * 784 + s];
}

// ---------------------------------------------------------------------------
// K1: fused pseudo-label + bilinear weight scatter + top-k candidate filter.
// One pass over cam (present classes only). grid = 2*784 blocks, 1 pixel/thread.
__global__ __launch_bounds__(256) void k_pseudo_filter(const float* __restrict__ cam,
                                                       const float* __restrict__ cls_label,
                                                       const float* __restrict__ hig_p,
                                                       const float* __restrict__ low_p,
                                                       const float* __restrict__ bg_p,
                                                       float* __restrict__ W,
                                                       int* __restrict__ counts,
                                                       int* __restrict__ candCnt,
                                                       float* __restrict__ candV,
                                                       int* __restrict__ candI) {
  int b = blockIdx.x / 784;
  int pix = (blockIdx.x % 784) * 256 + threadIdx.x;
  __shared__ int presList[NCLS];
  __shared__ int sNP, sNA;
  if (threadIdx.x == 0) {
    int np = 0, na = 0;
    for (int c = 0; c < NCLS; ++c) {
      if (cls_label[b * NCLS + c] != 0.0f) presList[np++] = c; else na++;
    }
    sNP = np; sNA = na;
  }
  __syncthreads();
  float hig = hig_p[0], low = low_p[0], bg = bg_p[0];
  const float* camb = cam + (size_t)b * NCLS * HW;
  float top1 = -1.0f, second = -1.0f;
  int idx1 = 0;
  int lane = threadIdx.x & 63;
  int np = sNP;
  for (int k = 0; k < np; ++k) {
    int cls = presList[k];
    float v = camb[(size_t)cls * HW + pix];
    // ascending class index + strict '>' == lowest-index tie-break (JAX top_k)
    if (v > top1) { second = top1; top1 = v; idx1 = cls; }
    else if (v > second) second = v;
    // top-k candidate append, wave-aggregated (1 atomic per wave per class)
    bool cand = (v >= TFILT);
    unsigned long long mask = __ballot(cand);
    if (mask) {
      int leader = (int)__ffsll(mask) - 1;
      int base = 0;
      if (lane == leader) base = atomicAdd(&candCnt[b * NCLS + cls], (int)__popcll(mask));
      base = __shfl(base, leader, 64);
      if (cand) {
        int pos = base + (int)__popcll(mask & ((1ull << lane) - 1ull));
        if (pos < CAPG) {
          candV[(size_t)(b * NCLS + cls) * CAPG + pos] = v;
          candI[(size_t)(b * NCLS + cls) * CAPG + pos] = pix;
        }
      }
    }
  }
  // absent classes contribute value-0 entries to the dense top-2
  if (sNA > 0) second = fmaxf(second, 0.0f);
  int ps = idx1 + 1;
  if (top1 < hig) ps = 255;
  if (top1 < low) ps = 0;
  if (top1 < bg)  ps = 0;
  if ((top1 - second < 0.3f) && (top1 > hig)) ps = 255;
  if (ps >= 1 && ps <= NCLS) {
    int cls = ps - 1;
    int y = pix / IMG_W, x = pix % IMG_W;
    float sy = (y + 0.5f) * 0.0625f - 0.5f; sy = fminf(fmaxf(sy, 0.0f), 27.0f);
    float sx = (x + 0.5f) * 0.0625f - 0.5f; sx = fminf(fmaxf(sx, 0.0f), 27.0f);
    int fy0 = (int)sy, fx0 = (int)sx;
    int fy1 = min(fy0 + 1, 27), fx1 = min(fx0 + 1, 27);
    float wy = sy - (float)fy0, wx = sx - (float)fx0;
    float* Wb = W + (size_t)(b * NCLS + cls) * 784;
    atomicAdd(&Wb[fy0 * 28 + fx0], (1.0f - wy) * (1.0f - wx));
    atomicAdd(&Wb[fy0 * 28 + fx1], (1.0f - wy) * wx);
    atomicAdd(&Wb[fy1 * 28 + fx0], wy * (1.0f - wx));
    atomicAdd(&Wb[fy1 * 28 + fx1], wy * wx);
    atomicAdd(&counts[b * NCLS + cls], 1);
  }
}

// ---------------------------------------------------------------------------
// K2: exact top-25 per (b,c) — only runs for present classes with count==0
// (topIdx is only consumed on the counts==0 branch). grid = 40 blocks.
__global__ __launch_bounds__(256) void k_select(const float* __restrict__ cam,
                                                const float* __restrict__ cls_label,
                                                const int* __restrict__ counts,
                                                const int* __restrict__ candCnt,
                                                const float* __restrict__ candV,
                                                const int* __restrict__ candI,
                                                int* __restrict__ topIdx) {
  int bc = blockIdx.x;
  if (cls_label[bc] == 0.0f) return;     // fsm row is zeroed anyway
  if (counts[bc] > 0) return;            // feat_mask branch -> topIdx unused
  __shared__ float cv[CAPG]; __shared__ int ci[CAPG];
  __shared__ float wv[4]; __shared__ int wi[4];
  __shared__ float selV; __shared__ int selI;
  int tid = threadIdx.x;
  int n = candCnt[bc];
  bool fb = (n < 25) || (n > CAPG);      // exact fallback (never in practice)
  if (!fb) {
    for (int p = tid; p < n; p += 256) {
      cv[p] = candV[(size_t)bc * CAPG + p];
      ci[p] = candI[(size_t)bc * CAPG + p];
    }
  }
  __syncthreads();
  const float* camc = cam + (size_t)bc * HW;   // lab==1 -> valid_cam == cam
  float lastV = 3.0e38f; int lastI = -1;
  for (int r = 0; r < 25; ++r) {
    float bv = -1.0e30f; int bi = 0x7fffffff;
    if (!fb) {
      for (int p = tid; p < n; p += 256) {
        float v = cv[p]; int i = ci[p];
        if (((v < lastV) || (v == lastV && i > lastI)) &&
            ((v > bv) || (v == bv && i < bi))) { bv = v; bi = i; }
      }
    } else {
      for (int p = tid; p < HW; p += 256) {
        float v = camc[p];
        if (((v < lastV) || (v == lastV && p > lastI)) &&
            ((v > bv) || (v == bv && p < bi))) { bv = v; bi = p; }
      }
    }
    // wave-level argmax (value desc, index asc), no barriers
    for (int off = 32; off > 0; off >>= 1) {
      float ov = __shfl_xor(bv, off, 64);
      int   oi = __shfl_xor(bi, off, 64);
      if (ov > bv || (ov == bv && oi < bi)) { bv = ov; bi = oi; }
    }
    if ((tid & 63) == 0) { wv[tid >> 6] = bv; wi[tid >> 6] = bi; }
    __syncthreads();
    if (tid == 0) {
      for (int w = 1; w < 4; ++w)
        if (wv[w] > bv || (wv[w] == bv && wi[w] < bi)) { bv = wv[w]; bi = wi[w]; }
      selV = bv; selI = bi;
      topIdx[bc * 25 + r] = bi;
    }
    __syncthreads();
    lastV = selV; lastI = selI;
  }
}

// ---------------------------------------------------------------------------
// K3: per (b,c) feature row. cnt>0 -> W-dot only; cnt==0 -> 25 gathers only.
__global__ __launch_bounds__(256) void k_features(const float* __restrict__ fmapT,
                                                  const float* __restrict__ W,
                                                  const int* __restrict__ counts,
                                                  const int* __restrict__ topIdx,
                                                  const float* __restrict__ cls_label,
                                                  float* __restrict__ fsm_g) {
  int bc = blockIdx.x;
  int b = bc / NCLS;
  int tid = threadIdx.x;
  if (cls_label[bc] == 0.0f) { fsm_g[(size_t)bc * 256 + tid] = 0.0f; return; }
  int cnt = counts[bc];
  const float* fT = fmapT + (size_t)b * 784 * 256;
  float res;
  if (cnt > 0) {
    __shared__ float sW[784];
    for (int s = tid; s < 784; s += 256) sW[s] = W[(size_t)bc * 784 + s];
    __syncthreads();
    float a0 = 0.0f, a1 = 0.0f, a2 = 0.0f, a3 = 0.0f;
#pragma unroll 4
    for (int s = 0; s < 784; s += 4) {
      a0 += sW[s]     * fT[(size_t)(s)     * 256 + tid];
      a1 += sW[s + 1] * fT[(size_t)(s + 1) * 256 + tid];
      a2 += sW[s + 2] * fT[(size_t)(s + 2) * 256 + tid];
      a3 += sW[s + 3] * fT[(size_t)(s + 3) * 256 + tid];
    }
    res = ((a0 + a1) + (a2 + a3)) / fmaxf((float)cnt, 1.0f);
  } else {
    float at = 0.0f;
    for (int r = 0; r < 25; ++r) {
      int p = topIdx[bc * 25 + r];
      int y = p / IMG_W, x = p % IMG_W;
      float sy = (y + 0.5f) * 0.0625f - 0.5f; sy = fminf(fmaxf(sy, 0.0f), 27.0f);
      float sx = (x + 0.5f) * 0.0625f - 0.5f; sx = fminf(fmaxf(sx, 0.0f), 27.0f);
      int fy0 = (int)sy, fx0 = (int)sx;
      int fy1 = min(fy0 + 1, 27), fx1 = min(fx0 + 1, 27);
      float wy = sy - (float)fy0, wx = sx - (float)fx0;
      at += (1.0f - wy) * (1.0f - wx) * fT[(size_t)(fy0 * 28 + fx0) * 256 + tid]
          + (1.0f - wy) * wx          * fT[(size_t)(fy0 * 28 + fx1) * 256 + tid]
          + wy          * (1.0f - wx) * fT[(size_t)(fy1 * 28 + fx0) * 256 + tid]
          + wy          * wx          * fT[(size_t)(fy1 * 28 + fx1) * 256 + tid];
    }
    res = at * (1.0f / 25.0f);
  }
  fsm_g[(size_t)bc * 256 + tid] = res;
}

// ---------------------------------------------------------------------------
// K4: sequential loss over b with EMA memory bank. Single block, 256 threads.
__global__ __launch_bounds__(256) void k_loss(const float* __restrict__ fsm_g,
                                              const float* __restrict__ cls_label,
                                              const float* __restrict__ proj_w,
                                              const float* __restrict__ fc_init,
                                              float* __restrict__ out) {
  __shared__ float sFsm[NCLS * LK];
  __shared__ float sFc[NCLS * LK];
  __shared__ float sPw[NCLS * LK];
  __shared__ float sMat[NCLS * NCLS];
  __shared__ float sRow[NCLS];
  __shared__ float sNormI[NCLS], sNormC[NCLS];
  __shared__ int   sQual[NCLS];
  __shared__ float sPres[2][NCLS];
  __shared__ float sScal[2];
  int tid = threadIdx.x;
  for (int r = 0; r < NCLS; ++r) {
    sFc[r * LK + tid] = fc_init[r * 256 + tid];
    sPw[r * LK + tid] = proj_w[r * 256 + tid];
  }
  if (tid < 40) sPres[tid / NCLS][tid % NCLS] = cls_label[tid];
  if (tid == 0) { sScal[0] = 0.0f; sScal[1] = 0.0f; }
  __syncthreads();

  for (int b = 0; b < 2; ++b) {
    for (int r = 0; r < NCLS; ++r) sFsm[r * LK + tid] = fsm_g[(b * NCLS + r) * 256 + tid];
    __syncthreads();
    if (tid < NCLS) {
      float s = 0.0f, t2 = 0.0f;
      for (int d = 0; d < 256; ++d) {
        float a = sFsm[tid * LK + d]; s += a * a;
        float f = sFc[tid * LK + d];  t2 += f * f;
      }
      sNormI[tid] = fmaxf(sqrtf(s), 1e-12f);
      sNormC[tid] = fmaxf(sqrtf(t2), 1e-12f);
    }
    __syncthreads();
    for (int pi = tid; pi < 400; pi += 256) {
      int i = pi / NCLS, j = pi % NCLS;
      float acc = 0.0f;
      for (int d = 0; d < 256; ++d) acc += sFsm[i * LK + d] * sFc[j * LK + d];
      float c0 = fabsf(acc / (sNormI[i] * sNormC[j]));
      sMat[pi] = fminf(fmaxf(c0, 1e-5f), 1.0f - 1e-5f);
    }
    __syncthreads();
    if (tid < NCLS) {
      float pres = (sPres[b][tid] > 0.5f) ? 1.0f : 0.0f;
      float rs = 0.0f, om = -3.0e38f;
      for (int j = 0; j < NCLS; ++j) {
        float c0 = sMat[tid * NCLS + j];
        float ident = (j == tid) ? pres : 0.0f;
        rs += ident * logf(c0) + (1.0f - ident) * log1pf(-c0);
        if (j != tid) om = fmaxf(om, c0);
      }
      sRow[tid] = rs;
      sQual[tid] = (pres > 0.5f && om < 0.6f) ? 1 : 0;
    }
    __syncthreads();
    if (tid == 0) {
      float s = 0.0f;
      for (int r = 0; r < NCLS; ++r) s += sRow[r];
      sScal[0] -= s / 400.0f;
    }
    __syncthreads();
    for (int pi = tid; pi < 400; pi += 256) {
      int i = pi / NCLS, j = pi % NCLS;
      float acc = 0.0f;
      for (int d = 0; d < 256; ++d) acc += sFsm[i * LK + d] * sPw[j * LK + d];
      sMat[pi] = acc;
    }
    __syncthreads();
    if (tid < NCLS) {
      float m = -3.0e38f;
      for (int j = 0; j < NCLS; ++j) m = fmaxf(m, sMat[tid * NCLS + j]);
      float S = 0.0f;
      for (int j = 0; j < NCLS; ++j) S += expf(sMat[tid * NCLS + j] - m);
      float ts = 0.0f;
      for (int j = 0; j < NCLS; ++j) {
        float p = expf(sMat[tid * NCLS + j] - m) / S;
        if (j == tid) ts += fmaxf(logf(p), -100.0f);
        else          ts += fmaxf(log1pf(-p), -100.0f);
      }
      sRow[tid] = -ts / 20.0f;
    }
    __syncthreads();
    if (tid == 0) {
      float add = 0.0f; int n = 0;
      for (int r = 0; r < NCLS; ++r) if (sQual[r]) { add += sRow[r]; n++; }
      float lc = sScal[1] + add;
      if (n > 0) lc = lc / fmaxf((float)n, 1.0f);
      sScal[1] = lc;
    }
    __syncthreads();
    for (int r = 0; r < NCLS; ++r)
      if (sQual[r]) sFc[r * LK + tid] = 0.95f * sFc[r * LK + tid] + 0.05f * sFsm[r * LK + tid];
    __syncthreads();
  }
  if (tid == 0) out[0] = sScal[0] + sScal[1];
}

// ---------------------------------------------------------------------------
extern "C" void kernel_launch(void* const* d_in, const int* in_sizes, int n_in,
                              void* d_out, int out_size, void* d_ws, size_t ws_size,
                              hipStream_t stream) {
  const float* fmap      = (const float*)d_in[0];
  const float* cam       = (const float*)d_in[1];
  const float* cls_label = (const float*)d_in[2];
  const float* proj_w    = (const float*)d_in[3];
  const float* fc_init   = (const float*)d_in[4];
  const float* hig       = (const float*)d_in[5];
  const float* low       = (const float*)d_in[6];
  const float* bg        = (const float*)d_in[7];
  float* out = (float*)d_out;

  char* ws = (char*)d_ws;
  float* W       = (float*)(ws);                 // 31360 floats (125440 B)
  int*   counts  = (int*)  (ws + 125440);        // 40 ints
  int*   candCnt = (int*)  (ws + 125600);        // 40 ints
  int*   topIdx  = (int*)  (ws + 125760);        // 1000 ints (4000 B)
  float* fsm     = (float*)(ws + 129760);        // 10240 floats (40960 B)
  float* candV   = (float*)(ws + 170720);        // 40*2560 floats (409600 B)
  int*   candI   = (int*)  (ws + 580320);        // 40*2560 ints   (409600 B)
  float* fmapT   = (float*)(ws + 989920);        // 401408 floats  (1605632 B)

  hipMemsetAsync(ws, 0, 125760, stream);         // zero W + counts + candCnt
  k_transpose    <<<1568, 256, 0, stream>>>(fmap, fmapT);
  k_pseudo_filter<<<1568, 256, 0, stream>>>(cam, cls_label, hig, low, bg,
                                            W, counts, candCnt, candV, candI);
  k_select       <<<  40, 256, 0, stream>>>(cam, cls_label, counts, candCnt, candV, candI, topIdx);
  k_features     <<<  40, 256, 0, stream>>>(fmapT, W, counts, topIdx, cls_label, fsm);
  k_loss         <<<   1, 256, 0, stream>>>(fsm, cls_label, proj_w, fc_init, out);
}